// Round 6
// baseline (499.168 us; speedup 1.0000x reference)
//
#include <hip/hip_runtime.h>
#include <math.h>

#define BS 2
#define C_DIM 256
#define N_DIM 4096
#define E_DIM 2048
#define P_DIM 32
#define NS1 32   // n-splits for proto1
#define FS2 8    // f-splits for proto2
#define KS2 2    // f-splits for final MFMA GEMM

typedef __attribute__((ext_vector_type(8))) short short8;
typedef __attribute__((ext_vector_type(4))) float f32x4;

__device__ __forceinline__ unsigned short f2bf(float f) {
  unsigned u = __float_as_uint(f);
  return (unsigned short)((u + 0x7FFFu + ((u >> 16) & 1u)) >> 16);
}

// ---------------------------------------------------------------------------
// A: K[b][n][p] = BN(proj_w @ vf), Ksq[b][n] = sum_p K^2.  grid 128, block 256
// ---------------------------------------------------------------------------
__global__ __launch_bounds__(256) void k_proj(
    const float* __restrict__ vf, const float* __restrict__ pw,
    const float* __restrict__ gamma, const float* __restrict__ beta,
    const float* __restrict__ mean, const float* __restrict__ var,
    float* __restrict__ Kf, float* __restrict__ Ksq) {
  __shared__ float w_s[P_DIM * C_DIM];
  __shared__ float part_s[4][64][P_DIM + 1];
  __shared__ float kt_s[64][P_DIM + 1];
  __shared__ float sc_s[P_DIM], sb_s[P_DIM], sm_s[P_DIM];

  const int tid = threadIdx.x;
  const int b = blockIdx.x >> 6;
  const int n0 = (blockIdx.x & 63) << 6;

  for (int i = tid; i < P_DIM * C_DIM; i += 256) w_s[i] = pw[i];
  if (tid < P_DIM) {
    sc_s[tid] = gamma[tid] / sqrtf(var[tid] + 1e-5f);
    sb_s[tid] = beta[tid];
    sm_s[tid] = mean[tid];
  }
  __syncthreads();

  const int nl = tid & 63, cs = tid >> 6;
  const float* vbase = vf + (size_t)b * C_DIM * N_DIM + n0 + nl;
  float acc[P_DIM];
#pragma unroll
  for (int p = 0; p < P_DIM; ++p) acc[p] = 0.f;
#pragma unroll 4
  for (int cc = 0; cc < 64; ++cc) {
    int c = cs * 64 + cc;
    float v = vbase[(size_t)c * N_DIM];
    const float* wc = &w_s[c];
#pragma unroll
    for (int p = 0; p < P_DIM; ++p) acc[p] = fmaf(wc[p * C_DIM], v, acc[p]);
  }
#pragma unroll
  for (int p = 0; p < P_DIM; ++p) part_s[cs][nl][p] = acc[p];
  __syncthreads();

  for (int i = tid; i < 64 * P_DIM; i += 256) {
    int n_l = i >> 5, p = i & 31;
    float s = ((part_s[0][n_l][p] + part_s[1][n_l][p]) + part_s[2][n_l][p]) +
              part_s[3][n_l][p];
    float k = (s - sm_s[p]) * sc_s[p] + sb_s[p];
    Kf[((size_t)(b * N_DIM + n0 + n_l)) * P_DIM + p] = k;
    kt_s[n_l][p] = k;
  }
  __syncthreads();
  if (tid < 64) {
    float q = 0.f;
#pragma unroll
    for (int p = 0; p < P_DIM; ++p) q = fmaf(kt_s[tid][p], kt_s[tid][p], q);
    Ksq[b * N_DIM + n0 + tid] = q;
  }
}

// ---------------------------------------------------------------------------
// A2: VT[b][n][c] = vf[b][c][n].  grid 512, block 256
// ---------------------------------------------------------------------------
__global__ __launch_bounds__(256) void k_transpose(const float* __restrict__ vf,
                                                   float* __restrict__ VT) {
  __shared__ float t_s[64][65];
  const int tid = threadIdx.x;
  const int b = blockIdx.x >> 8;
  const int n0 = ((blockIdx.x >> 2) & 63) << 6;
  const int c0 = (blockIdx.x & 3) << 6;
  const float* src = vf + (size_t)b * C_DIM * N_DIM;
#pragma unroll
  for (int i = 0; i < 16; ++i) {
    int idx = tid + i * 256;
    int n_l = idx & 63, c_l = idx >> 6;
    t_s[c_l][n_l] = src[(size_t)(c0 + c_l) * N_DIM + n0 + n_l];
  }
  __syncthreads();
  float* dst = VT + (size_t)b * N_DIM * C_DIM;
#pragma unroll
  for (int i = 0; i < 16; ++i) {
    int idx = tid + i * 256;
    int c_l = idx & 63, n_l = idx >> 6;
    dst[(size_t)(n0 + n_l) * C_DIM + c0 + c_l] = t_s[c_l][n_l];
  }
}

// ---------------------------------------------------------------------------
// A3: ied_h = bf16(ied).  8,388,608 elems. grid 4096, block 256, 8/thread
// ---------------------------------------------------------------------------
__global__ __launch_bounds__(256) void k_tobf(const float* __restrict__ src,
                                              short* __restrict__ dst) {
  size_t idx = ((size_t)blockIdx.x * 256 + threadIdx.x) * 8;
  const float4* s4 = (const float4*)(src + idx);
  float4 v0 = s4[0], v1 = s4[1];
  short8 h;
  h[0] = (short)f2bf(v0.x); h[1] = (short)f2bf(v0.y);
  h[2] = (short)f2bf(v0.z); h[3] = (short)f2bf(v0.w);
  h[4] = (short)f2bf(v1.x); h[5] = (short)f2bf(v1.y);
  h[6] = (short)f2bf(v1.z); h[7] = (short)f2bf(v1.w);
  *(short8*)(dst + idx) = h;
}

// ---------------------------------------------------------------------------
// B1: P1part[ns][b][e][p] = sum_{n in 128-chunk} inc[b][n][e]*K[b][n][p]
// grid 256 (= bs * 4 etiles(512e) * 32 nsplits), block 256, 2 e per thread.
// Accumulation order over n identical to previous version (bitwise-same).
// ---------------------------------------------------------------------------
__global__ __launch_bounds__(256) void k_proto1(const float* __restrict__ inc,
                                                const float* __restrict__ Kf,
                                                float* __restrict__ part) {
  __shared__ float k_s[64][P_DIM];
  const int tid = threadIdx.x;
  const int b = blockIdx.x >> 7;
  const int et = (blockIdx.x >> 5) & 3;
  const int ns = blockIdx.x & 31;
  const int e0 = et << 9;
  const int nbase = ns << 7;

  float acc0[P_DIM], acc1[P_DIM];
#pragma unroll
  for (int p = 0; p < P_DIM; ++p) { acc0[p] = 0.f; acc1[p] = 0.f; }

  for (int nt = 0; nt < 2; ++nt) {
    int n0 = nbase + nt * 64;
#pragma unroll
    for (int i = 0; i < 8; ++i) {
      int idx = tid + i * 256;
      ((float*)k_s)[idx] = Kf[((size_t)(b * N_DIM + n0)) * P_DIM + idx];
    }
    __syncthreads();
#pragma unroll 8
    for (int nn = 0; nn < 64; ++nn) {
      const float* irow = inc + ((size_t)(b * N_DIM + n0 + nn)) * E_DIM + e0;
      float va = irow[tid];
      float vb = irow[tid + 256];
      const float4* kv4 = (const float4*)k_s[nn];
#pragma unroll
      for (int q = 0; q < 8; ++q) {
        float4 kv = kv4[q];
        acc0[4 * q + 0] = fmaf(va, kv.x, acc0[4 * q + 0]);
        acc0[4 * q + 1] = fmaf(va, kv.y, acc0[4 * q + 1]);
        acc0[4 * q + 2] = fmaf(va, kv.z, acc0[4 * q + 2]);
        acc0[4 * q + 3] = fmaf(va, kv.w, acc0[4 * q + 3]);
        acc1[4 * q + 0] = fmaf(vb, kv.x, acc1[4 * q + 0]);
        acc1[4 * q + 1] = fmaf(vb, kv.y, acc1[4 * q + 1]);
        acc1[4 * q + 2] = fmaf(vb, kv.z, acc1[4 * q + 2]);
        acc1[4 * q + 3] = fmaf(vb, kv.w, acc1[4 * q + 3]);
      }
    }
    __syncthreads();
  }
  float* dst0 = part + (size_t)ns * (BS * E_DIM * P_DIM) +
                ((size_t)(b * E_DIM + e0 + tid)) * P_DIM;
  float* dst1 = dst0 + 256 * P_DIM;
#pragma unroll
  for (int q = 0; q < 8; ++q) {
    ((float4*)dst0)[q] = make_float4(acc0[4 * q + 0], acc0[4 * q + 1],
                                     acc0[4 * q + 2], acc0[4 * q + 3]);
    ((float4*)dst1)[q] = make_float4(acc1[4 * q + 0], acc1[4 * q + 1],
                                     acc1[4 * q + 2], acc1[4 * q + 3]);
  }
}

// ---------------------------------------------------------------------------
// B2: proto1 = sum of 32 partials.  grid 512, block 256
// ---------------------------------------------------------------------------
__global__ __launch_bounds__(256) void k_red32(const float* __restrict__ part,
                                               float* __restrict__ outp) {
  int g = blockIdx.x * 256 + threadIdx.x;
  float v = 0.f;
#pragma unroll
  for (int s = 0; s < NS1; ++s)
    v += part[(size_t)s * (BS * E_DIM * P_DIM) + g];
  outp[g] = v;
}

// ---------------------------------------------------------------------------
// B3: P2part[fs][b][e][p] = sum_{f in 256-chunk} ied[b][e][f]*proto1[b][f][p]
// grid 256 (= bs * 16 etiles(128e) * 8 fsplits), block 256, [2e][8p]/thread.
// Accumulation order over f identical to previous version (bitwise-same).
// ---------------------------------------------------------------------------
__global__ __launch_bounds__(256) void k_proto2(const float* __restrict__ ied,
                                                const float* __restrict__ proto1,
                                                float* __restrict__ part) {
  __shared__ float inv_s[128][33];
  __shared__ float p1_s[32][P_DIM];
  const int tid = threadIdx.x;
  const int b = blockIdx.x >> 7;
  const int et = (blockIdx.x >> 3) & 15;
  const int fs = blockIdx.x & 7;
  const int e0 = et << 7;
  const int fbase = fs << 8;
  const int e_l = tid & 63, pg = tid >> 6;

  float acc0[8], acc1[8];
#pragma unroll
  for (int q = 0; q < 8; ++q) { acc0[q] = 0.f; acc1[q] = 0.f; }

  for (int ft = 0; ft < 8; ++ft) {
    int f0 = fbase + ft * 32;
    __syncthreads();
#pragma unroll
    for (int i = 0; i < 16; ++i) {
      int idx = tid + i * 256;
      int e_r = idx >> 5, f_l = idx & 31;
      inv_s[e_r][f_l] =
          ied[((size_t)(b * E_DIM + e0 + e_r)) * E_DIM + f0 + f_l];
    }
#pragma unroll
    for (int i = 0; i < 4; ++i) {
      int idx = tid + i * 256;
      ((float*)p1_s)[idx] = proto1[((size_t)(b * E_DIM + f0)) * P_DIM + idx];
    }
    __syncthreads();
#pragma unroll
    for (int ff = 0; ff < 32; ++ff) {
      float a0 = inv_s[e_l][ff];
      float a1 = inv_s[e_l + 64][ff];
      const float4* pv4 = (const float4*)&p1_s[ff][pg * 8];
      float4 pv0 = pv4[0], pv1 = pv4[1];
      acc0[0] = fmaf(a0, pv0.x, acc0[0]);
      acc0[1] = fmaf(a0, pv0.y, acc0[1]);
      acc0[2] = fmaf(a0, pv0.z, acc0[2]);
      acc0[3] = fmaf(a0, pv0.w, acc0[3]);
      acc0[4] = fmaf(a0, pv1.x, acc0[4]);
      acc0[5] = fmaf(a0, pv1.y, acc0[5]);
      acc0[6] = fmaf(a0, pv1.z, acc0[6]);
      acc0[7] = fmaf(a0, pv1.w, acc0[7]);
      acc1[0] = fmaf(a1, pv0.x, acc1[0]);
      acc1[1] = fmaf(a1, pv0.y, acc1[1]);
      acc1[2] = fmaf(a1, pv0.z, acc1[2]);
      acc1[3] = fmaf(a1, pv0.w, acc1[3]);
      acc1[4] = fmaf(a1, pv1.x, acc1[4]);
      acc1[5] = fmaf(a1, pv1.y, acc1[5]);
      acc1[6] = fmaf(a1, pv1.z, acc1[6]);
      acc1[7] = fmaf(a1, pv1.w, acc1[7]);
    }
  }
  float* dst0 = part + (size_t)fs * (BS * E_DIM * P_DIM) +
                ((size_t)(b * E_DIM + e0 + e_l)) * P_DIM + pg * 8;
  float* dst1 = dst0 + 64 * P_DIM;
  ((float4*)dst0)[0] = make_float4(acc0[0], acc0[1], acc0[2], acc0[3]);
  ((float4*)dst0)[1] = make_float4(acc0[4], acc0[5], acc0[6], acc0[7]);
  ((float4*)dst1)[0] = make_float4(acc1[0], acc1[1], acc1[2], acc1[3]);
  ((float4*)dst1)[1] = make_float4(acc1[4], acc1[5], acc1[6], acc1[7]);
}

// ---------------------------------------------------------------------------
// B4: proto = sum of 8 partials; proto_sq = rownorm^2.  grid 512, block 256
// ---------------------------------------------------------------------------
__global__ __launch_bounds__(256) void k_red8sq(const float* __restrict__ part,
                                                float* __restrict__ proto,
                                                float* __restrict__ psq) {
  int g = blockIdx.x * 256 + threadIdx.x;
  float v = 0.f;
#pragma unroll
  for (int s = 0; s < FS2; ++s)
    v += part[(size_t)s * (BS * E_DIM * P_DIM) + g];
  proto[g] = v;
  float q = v * v;
#pragma unroll
  for (int m = 1; m <= 16; m <<= 1) q += __shfl_xor(q, m, 64);
  if ((threadIdx.x & 31) == 0) psq[g >> 5] = q;
}

// ---------------------------------------------------------------------------
// C1: per-(edge, 128-n-chunk) max of g = 2*<proto_e,K_n> - Ksq_n
// grid 1024 (= bs * 16 etiles(128e) * 32 chunks), block 256.
// 8x8 register microtile; p-major padded LDS; same fmaf chain as before.
// ---------------------------------------------------------------------------
__global__ __launch_bounds__(256) void k_gmax(const float* __restrict__ Kf,
                                              const float* __restrict__ Ksq,
                                              const float* __restrict__ proto,
                                              float* __restrict__ chunkg) {
  __shared__ float a_s[P_DIM][132];  // [p][e], 128 e
  __shared__ float b_s[P_DIM][132];  // [p][n], 128 n
  __shared__ float q_s[128];
  const int tid = threadIdx.x;
  const int b = blockIdx.x >> 9;
  const int et = (blockIdx.x >> 5) & 15;
  const int ch = blockIdx.x & 31;
  const int e0 = et << 7, n0 = ch << 7;

#pragma unroll
  for (int i = 0; i < 16; ++i) {
    int idx = tid + i * 256;
    int e = idx >> 5, p = idx & 31;
    a_s[p][e] = proto[((size_t)(b * E_DIM + e0 + e)) * P_DIM + p];
  }
#pragma unroll
  for (int i = 0; i < 16; ++i) {
    int idx = tid + i * 256;
    int n = idx >> 5, p = idx & 31;
    b_s[p][n] = Kf[((size_t)(b * N_DIM + n0 + n)) * P_DIM + p];
  }
  if (tid < 128) q_s[tid] = Ksq[b * N_DIM + n0 + tid];
  __syncthreads();

  const int ig = tid >> 4, j = tid & 15;  // ig: e-group(16x8), j: n-group(16x8)
  float acc[8][8];
#pragma unroll
  for (int r = 0; r < 8; ++r)
#pragma unroll
    for (int c = 0; c < 8; ++c) acc[r][c] = 0.f;

#pragma unroll
  for (int p = 0; p < P_DIM; ++p) {
    float4 av0 = *(const float4*)&a_s[p][ig * 8];
    float4 av1 = *(const float4*)&a_s[p][ig * 8 + 4];
    float4 bv0 = *(const float4*)&b_s[p][j * 8];
    float4 bv1 = *(const float4*)&b_s[p][j * 8 + 4];
    float ae[8] = {av0.x, av0.y, av0.z, av0.w, av1.x, av1.y, av1.z, av1.w};
    float bn[8] = {bv0.x, bv0.y, bv0.z, bv0.w, bv1.x, bv1.y, bv1.z, bv1.w};
#pragma unroll
    for (int r = 0; r < 8; ++r)
#pragma unroll
      for (int c = 0; c < 8; ++c)
        acc[r][c] = fmaf(ae[r], bn[c], acc[r][c]);
  }

#pragma unroll
  for (int r = 0; r < 8; ++r) {
    float m = -INFINITY;
#pragma unroll
    for (int c = 0; c < 8; ++c)
      m = fmaxf(m, fmaf(2.0f, acc[r][c], -q_s[j * 8 + c]));
    m = fmaxf(m, __shfl_xor(m, 1, 64));
    m = fmaxf(m, __shfl_xor(m, 2, 64));
    m = fmaxf(m, __shfl_xor(m, 4, 64));
    m = fmaxf(m, __shfl_xor(m, 8, 64));
    if (j == 0)
      chunkg[((size_t)(b * E_DIM + e0 + ig * 8 + r)) * 32 + ch] = m;
  }
}

// ---------------------------------------------------------------------------
// C2: per-edge sparse softmax-aggregate. One wave per edge.
// grid 1024, block 256 (4 waves).
// ---------------------------------------------------------------------------
__device__ __forceinline__ float edge_logit(const float* __restrict__ Kb,
                                            const float* __restrict__ Qb,
                                            const float* pr, float psqv,
                                            int n) {
  const float4* kp = (const float4*)(Kb + (size_t)n * P_DIM);
  float i0 = 0.f, i1 = 0.f, i2 = 0.f, i3 = 0.f;
#pragma unroll
  for (int q = 0; q < 8; ++q) {
    float4 kv = kp[q];
    i0 = fmaf(pr[4 * q + 0], kv.x, i0);
    i1 = fmaf(pr[4 * q + 1], kv.y, i1);
    i2 = fmaf(pr[4 * q + 2], kv.z, i2);
    i3 = fmaf(pr[4 * q + 3], kv.w, i3);
  }
  float inner = (i0 + i1) + (i2 + i3);
  float cost = fmaf(-2.0f, inner, psqv + Qb[n]);
  const float tau_eps = 0.1f + 1e-8f;
  return (-cost) / tau_eps;
}

__global__ __launch_bounds__(256) void k_sparse(
    const float* __restrict__ Kf, const float* __restrict__ Ksq,
    const float* __restrict__ proto, const float* __restrict__ psq,
    const float* __restrict__ VT, const float* __restrict__ chunkg,
    float* __restrict__ EF0) {
  const int tid = threadIdx.x;
  const int lane = tid & 63;
  const int eg = blockIdx.x * 4 + (tid >> 6);
  const int b = eg >> 11;
  const float* Kb = Kf + (size_t)b * N_DIM * P_DIM;
  const float* Qb = Ksq + (size_t)b * N_DIM;

  float cg = (lane < 32) ? chunkg[(size_t)eg * 32 + lane] : -INFINITY;
  float gmax = cg;
#pragma unroll
  for (int m = 1; m <= 32; m <<= 1) gmax = fmaxf(gmax, __shfl_xor(gmax, m, 64));
  unsigned long long live = __ballot(cg > gmax - 20.0f);

  float pr[P_DIM];
  const float* pe = proto + (size_t)eg * P_DIM;
#pragma unroll
  for (int p = 0; p < P_DIM; ++p) pr[p] = pe[p];
  const float psqv = psq[eg];

  float L = -INFINITY;
  unsigned long long m0 = live;
  while (m0) {
    int c = __ffsll(m0) - 1;
    m0 &= m0 - 1;
    int n = (c << 7) + lane;
    L = fmaxf(L, edge_logit(Kb, Qb, pr, psqv, n));
    L = fmaxf(L, edge_logit(Kb, Qb, pr, psqv, n + 64));
  }
#pragma unroll
  for (int m = 1; m <= 32; m <<= 1) L = fmaxf(L, __shfl_xor(L, m, 64));

  float4 acc = make_float4(0.f, 0.f, 0.f, 0.f);
  float sw = 0.f;
  const float* Vb = VT + (size_t)b * N_DIM * C_DIM;
  m0 = live;
  while (m0) {
    int c = __ffsll(m0) - 1;
    m0 &= m0 - 1;
#pragma unroll
    for (int h = 0; h < 2; ++h) {
      int n = (c << 7) + (h << 6) + lane;
      float l = edge_logit(Kb, Qb, pr, psqv, n);
      float d = l - L;
      float wgt = (d > -25.0f) ? expf(d) : 0.f;
      sw += wgt;
      unsigned long long hits = __ballot(wgt > 0.f);
      while (hits) {
        int src = __ffsll(hits) - 1;
        hits &= hits - 1;
        float wv = __shfl(wgt, src, 64);
        int nv = (c << 7) + (h << 6) + src;
        const float4 vrow =
            *(const float4*)(Vb + (size_t)nv * C_DIM + (lane << 2));
        acc.x = fmaf(wv, vrow.x, acc.x);
        acc.y = fmaf(wv, vrow.y, acc.y);
        acc.z = fmaf(wv, vrow.z, acc.z);
        acc.w = fmaf(wv, vrow.w, acc.w);
      }
    }
  }
#pragma unroll
  for (int m = 1; m <= 32; m <<= 1) sw += __shfl_xor(sw, m, 64);

  float* dst = EF0 + (size_t)eg * C_DIM + (lane << 2);
  *(float4*)dst =
      make_float4(acc.x / sw, acc.y / sw, acc.z / sw, acc.w / sw);
}

// ---------------------------------------------------------------------------
// C3: EF0t[b][c][f] = bf16(EF0[b][f][c]).  grid 256, block 256, 64x64 tiles
// ---------------------------------------------------------------------------
__global__ __launch_bounds__(256) void k_ef0t(const float* __restrict__ EF0,
                                              short* __restrict__ EF0t) {
  __shared__ short sh[64][72];
  const int tid = threadIdx.x;
  const int b = blockIdx.x >> 7;
  const int ft = (blockIdx.x >> 2) & 31;
  const int ct = blockIdx.x & 3;
  const int f0 = ft << 6, c0 = ct << 6;
#pragma unroll
  for (int i = 0; i < 4; ++i) {
    int idx = tid + i * 256;
    int f_l = idx >> 4, cc = idx & 15;
    float4 v =
        *(const float4*)&EF0[((size_t)(b * E_DIM + f0 + f_l)) * C_DIM + c0 +
                             cc * 4];
    sh[cc * 4 + 0][f_l] = (short)f2bf(v.x);
    sh[cc * 4 + 1][f_l] = (short)f2bf(v.y);
    sh[cc * 4 + 2][f_l] = (short)f2bf(v.z);
    sh[cc * 4 + 3][f_l] = (short)f2bf(v.w);
  }
  __syncthreads();
#pragma unroll
  for (int i = 0; i < 2; ++i) {
    int idx = tid + i * 256;
    int c_l = idx >> 3, ch = idx & 7;
    short8 v = *(const short8*)&sh[c_l][ch * 8];
    *(short8*)&EF0t[((size_t)(b * C_DIM + c0 + c_l)) * E_DIM + f0 + ch * 8] = v;
  }
}

// ---------------------------------------------------------------------------
// D: bf16 MFMA GEMM. partOut[ks][b][c][e] = sum_{f in 1024-chunk}
//    ied[b][e][f] * EF0[b][f][c], via D[e][c] = A[e][f]*Bt[c][f] tiles.
// grid 512, block 256 (4 waves). Tile 64e x 64c, BK=64, wave quad 32x32.
// LDS XOR-swizzle (byte ^= (row&7)<<4) -> conflict-free ds_read_b128.
// ---------------------------------------------------------------------------
__device__ __forceinline__ short8 lds_frag(const short* s, int row, int k) {
  int off = (((row << 6) + k) << 1) ^ ((row & 7) << 4);
  return *(const short8*)((const char*)s + off);
}
__device__ __forceinline__ void lds_put(short* s, int row, int k, short8 v) {
  int off = (((row << 6) + k) << 1) ^ ((row & 7) << 4);
  *(short8*)((char*)s + off) = v;
}

__global__ __launch_bounds__(256) void k_final_mfma(
    const short* __restrict__ Ah, const short* __restrict__ Bh,
    float* __restrict__ part) {
  __shared__ short As[64 * 64];
  __shared__ short Bs[64 * 64];
  __shared__ float Cs[64][68];

  const int tid = threadIdx.x;
  const int lane = tid & 63;
  const int w = tid >> 6;
  const int ks = blockIdx.x & 1;
  const int ct = (blockIdx.x >> 1) & 3;
  const int et = (blockIdx.x >> 3) & 31;
  const int b = blockIdx.x >> 8;
  const int e0 = et << 6, c0 = ct << 6;
  const int fbase = ks << 10;

  const int we = (w >> 1) << 5;   // wave e-quadrant offset
  const int wc = (w & 1) << 5;    // wave c-quadrant offset
  const int row = tid >> 2, ch = tid & 3;

  const short* gA = Ah + ((size_t)(b * E_DIM + e0 + row)) * E_DIM + fbase;
  const short* gB = Bh + ((size_t)(b * C_DIM + c0 + row)) * E_DIM + fbase;

  f32x4 z = {0.f, 0.f, 0.f, 0.f};
  f32x4 acc00 = z, acc01 = z, acc10 = z, acc11 = z;

  for (int kt = 0; kt < 16; ++kt) {
    const int f0 = kt << 6;
    const short8* pa = (const short8*)(gA + f0 + ch * 16);
    const short8* pb = (const short8*)(gB + f0 + ch * 16);
    short8 a0 = pa[0], a1 = pa[1];
    short8 b0 = pb[0], b1 = pb[1];
    lds_put(As, row, ch * 16, a0);
    lds_put(As, row, ch * 16 + 8, a1);
    lds_put(Bs, row, ch * 16, b0);
    lds_put(Bs, row, ch * 16 + 8, b1);
    __syncthreads();
#pragma unroll
    for (int s = 0; s < 2; ++s) {
      const int kb = (s << 5) + ((lane >> 4) << 3);
      short8 fa0 = lds_frag(As, we + (lane & 15), kb);
      short8 fa1 = lds_frag(As, we + 16 + (lane & 15), kb);
      short8 fb0 = lds_frag(Bs, wc + (lane & 15), kb);
      short8 fb1 = lds_frag(Bs, wc + 16 + (lane & 15), kb);
      acc00 = __builtin_amdgcn_mfma_f32_16x16x32_bf16(fa0, fb0, acc00, 0, 0, 0);
      acc01 = __builtin_amdgcn_mfma_f32_16x16x32_bf16(fa0, fb1, acc01, 0, 0, 0);
      acc10 = __builtin_amdgcn_mfma_f32_16x16x32_bf16(fa1, fb0, acc10, 0, 0, 0);
      acc11 = __builtin_amdgcn_mfma_f32_16x16x32_bf16(fa1, fb1, acc11, 0, 0, 0);
    }
    __syncthreads();
  }

  // epilogue: stage transposed [c][e] in LDS, then coalesced fp32 writes
  const int fr = lane & 15, fq = lane >> 4;
#pragma unroll
  for (int r = 0; r < 4; ++r) {
    Cs[wc + fr][we + fq * 4 + r] = acc00[r];
    Cs[wc + 16 + fr][we + fq * 4 + r] = acc01[r];
    Cs[wc + fr][we + 16 + fq * 4 + r] = acc10[r];
    Cs[wc + 16 + fr][we + 16 + fq * 4 + r] = acc11[r];
  }
  __syncthreads();
  {
    const int c_l = tid >> 2, cch = tid & 3;
    float* dst = part + (size_t)ks * (BS * C_DIM * E_DIM) +
                 ((size_t)(b * C_DIM + c0 + c_l)) * E_DIM + e0;
#pragma unroll
    for (int r = 0; r < 4; ++r) {
      float4 v = *(const float4*)&Cs[c_l][cch * 16 + r * 4];
      *(float4*)&dst[cch * 16 + r * 4] = v;
    }
  }
}

// ---------------------------------------------------------------------------
// D2: out = sum of KS2 partials (float4).  grid 1024, block 256
// ---------------------------------------------------------------------------
__global__ __launch_bounds__(256) void k_redout(const float* __restrict__ part,
                                                float* __restrict__ out) {
  int g = blockIdx.x * 256 + threadIdx.x;
  const float4* p4 = (const float4*)part;
  float4 v = p4[g];
#pragma unroll
  for (int s = 1; s < KS2; ++s) {
    float4 w = p4[(size_t)s * (BS * C_DIM * E_DIM / 4) + g];
    v.x += w.x; v.y += w.y; v.z += w.z; v.w += w.w;
  }
  ((float4*)out)[g] = v;
}

// ---------------------------------------------------------------------------
extern "C" void kernel_launch(void* const* d_in, const int* in_sizes, int n_in,
                              void* d_out, int out_size, void* d_ws,
                              size_t ws_size, hipStream_t stream) {
  (void)in_sizes; (void)n_in; (void)out_size; (void)ws_size;
  const float* vf  = (const float*)d_in[0];
  const float* inc = (const float*)d_in[1];
  const float* ied = (const float*)d_in[2];
  const float* pw  = (const float*)d_in[5];
  const float* gm  = (const float*)d_in[6];
  const float* bt  = (const float*)d_in[7];
  const float* mn  = (const float*)d_in[8];
  const float* vr  = (const float*)d_in[9];
  float* out = (float*)d_out;

  float* ws = (float*)d_ws;
  float* VT      = ws;                  // 2,097,152 f
  float* Kf      = VT + 2097152;        //   262,144
  float* Ksq     = Kf + 262144;         //     8,192
  float* proto1  = Ksq + 8192;          //   131,072
  float* proto   = proto1 + 131072;     //   131,072
  float* psq     = proto + 131072;      //     4,096
  float* P1p     = psq + 4096;          // 32*131,072 = 4,194,304
  float* partOut = P1p;                 // alias: 2*1,048,576 (disjoint lifetime)
  float* P2p     = P1p + 4194304;       //  8*131,072 = 1,048,576
  float* EF0     = P2p + 1048576;       // 1,048,576
  float* chunkg  = EF0 + 1048576;       //   131,072
  short* ied_h   = (short*)(chunkg + 131072);  // 8,388,608 shorts
  short* EF0t    = (short*)(chunkg + 131072 + 4194304);  // 1,048,576 shorts
  // total ~55.2 MB

  k_proj<<<dim3(128), dim3(256), 0, stream>>>(vf, pw, gm, bt, mn, vr, Kf, Ksq);
  k_transpose<<<dim3(512), dim3(256), 0, stream>>>(vf, VT);
  k_tobf<<<dim3(4096), dim3(256), 0, stream>>>(ied, ied_h);
  k_proto1<<<dim3(256), dim3(256), 0, stream>>>(inc, Kf, P1p);
  k_red32<<<dim3(512), dim3(256), 0, stream>>>(P1p, proto1);
  k_proto2<<<dim3(256), dim3(256), 0, stream>>>(ied, proto1, P2p);
  k_red8sq<<<dim3(512), dim3(256), 0, stream>>>(P2p, proto, psq);
  k_gmax<<<dim3(1024), dim3(256), 0, stream>>>(Kf, Ksq, proto, chunkg);
  k_sparse<<<dim3(1024), dim3(256), 0, stream>>>(Kf, Ksq, proto, psq, VT,
                                                 chunkg, EF0);
  k_ef0t<<<dim3(256), dim3(256), 0, stream>>>(EF0, EF0t);
  k_final_mfma<<<dim3(512), dim3(256), 0, stream>>>(ied_h, EF0t, partOut);
  k_redout<<<dim3(1024), dim3(256), 0, stream>>>(partOut, out);
}

// Round 7
// 160.996 us; speedup vs baseline: 3.1005x; 3.1005x over previous
//
#include <hip/hip_runtime.h>
#include <math.h>

#define BS 2
#define C_DIM 256
#define N_DIM 4096
#define E_DIM 2048
#define P_DIM 32
#define NS1 32   // n-splits for proto1
#define FS2 8    // f-splits for proto2
#define KS2 2    // f-splits for final MFMA GEMM

typedef __attribute__((ext_vector_type(8))) short short8;
typedef __attribute__((ext_vector_type(4))) float f32x4;

__device__ __forceinline__ unsigned short f2bf(float f) {
  unsigned u = __float_as_uint(f);
  return (unsigned short)((u + 0x7FFFu + ((u >> 16) & 1u)) >> 16);
}

// ---------------------------------------------------------------------------
// A: K[b][n][p] = BN(proj_w @ vf), Ksq[b][n] = sum_p K^2.  grid 128, block 256
// ---------------------------------------------------------------------------
__global__ __launch_bounds__(256) void k_proj(
    const float* __restrict__ vf, const float* __restrict__ pw,
    const float* __restrict__ gamma, const float* __restrict__ beta,
    const float* __restrict__ mean, const float* __restrict__ var,
    float* __restrict__ Kf, float* __restrict__ Ksq) {
  __shared__ float w_s[P_DIM * C_DIM];
  __shared__ float part_s[4][64][P_DIM + 1];
  __shared__ float kt_s[64][P_DIM + 1];
  __shared__ float sc_s[P_DIM], sb_s[P_DIM], sm_s[P_DIM];

  const int tid = threadIdx.x;
  const int b = blockIdx.x >> 6;
  const int n0 = (blockIdx.x & 63) << 6;

  for (int i = tid; i < P_DIM * C_DIM; i += 256) w_s[i] = pw[i];
  if (tid < P_DIM) {
    sc_s[tid] = gamma[tid] / sqrtf(var[tid] + 1e-5f);
    sb_s[tid] = beta[tid];
    sm_s[tid] = mean[tid];
  }
  __syncthreads();

  const int nl = tid & 63, cs = tid >> 6;
  const float* vbase = vf + (size_t)b * C_DIM * N_DIM + n0 + nl;
  float acc[P_DIM];
#pragma unroll
  for (int p = 0; p < P_DIM; ++p) acc[p] = 0.f;
#pragma unroll 4
  for (int cc = 0; cc < 64; ++cc) {
    int c = cs * 64 + cc;
    float v = vbase[(size_t)c * N_DIM];
    const float* wc = &w_s[c];
#pragma unroll
    for (int p = 0; p < P_DIM; ++p) acc[p] = fmaf(wc[p * C_DIM], v, acc[p]);
  }
#pragma unroll
  for (int p = 0; p < P_DIM; ++p) part_s[cs][nl][p] = acc[p];
  __syncthreads();

  for (int i = tid; i < 64 * P_DIM; i += 256) {
    int n_l = i >> 5, p = i & 31;
    float s = ((part_s[0][n_l][p] + part_s[1][n_l][p]) + part_s[2][n_l][p]) +
              part_s[3][n_l][p];
    float k = (s - sm_s[p]) * sc_s[p] + sb_s[p];
    Kf[((size_t)(b * N_DIM + n0 + n_l)) * P_DIM + p] = k;
    kt_s[n_l][p] = k;
  }
  __syncthreads();
  if (tid < 64) {
    float q = 0.f;
#pragma unroll
    for (int p = 0; p < P_DIM; ++p) q = fmaf(kt_s[tid][p], kt_s[tid][p], q);
    Ksq[b * N_DIM + n0 + tid] = q;
  }
}

// ---------------------------------------------------------------------------
// A2: VT[b][n][c] = vf[b][c][n].  grid 512, block 256
// ---------------------------------------------------------------------------
__global__ __launch_bounds__(256) void k_transpose(const float* __restrict__ vf,
                                                   float* __restrict__ VT) {
  __shared__ float t_s[64][65];
  const int tid = threadIdx.x;
  const int b = blockIdx.x >> 8;
  const int n0 = ((blockIdx.x >> 2) & 63) << 6;
  const int c0 = (blockIdx.x & 3) << 6;
  const float* src = vf + (size_t)b * C_DIM * N_DIM;
#pragma unroll
  for (int i = 0; i < 16; ++i) {
    int idx = tid + i * 256;
    int n_l = idx & 63, c_l = idx >> 6;
    t_s[c_l][n_l] = src[(size_t)(c0 + c_l) * N_DIM + n0 + n_l];
  }
  __syncthreads();
  float* dst = VT + (size_t)b * N_DIM * C_DIM;
#pragma unroll
  for (int i = 0; i < 16; ++i) {
    int idx = tid + i * 256;
    int c_l = idx & 63, n_l = idx >> 6;
    dst[(size_t)(n0 + n_l) * C_DIM + c0 + c_l] = t_s[c_l][n_l];
  }
}

// ---------------------------------------------------------------------------
// A3: ied_h = bf16(ied).  8,388,608 elems. grid 4096, block 256, 8/thread
// ---------------------------------------------------------------------------
__global__ __launch_bounds__(256) void k_tobf(const float* __restrict__ src,
                                              short* __restrict__ dst) {
  size_t idx = ((size_t)blockIdx.x * 256 + threadIdx.x) * 8;
  const float4* s4 = (const float4*)(src + idx);
  float4 v0 = s4[0], v1 = s4[1];
  short8 h;
  h[0] = (short)f2bf(v0.x); h[1] = (short)f2bf(v0.y);
  h[2] = (short)f2bf(v0.z); h[3] = (short)f2bf(v0.w);
  h[4] = (short)f2bf(v1.x); h[5] = (short)f2bf(v1.y);
  h[6] = (short)f2bf(v1.z); h[7] = (short)f2bf(v1.w);
  *(short8*)(dst + idx) = h;
}

// ---------------------------------------------------------------------------
// B1: P1part[ns][b][e][p] = sum_{n in 128-chunk} inc[b][n][e]*K[b][n][p]
// grid 256 (= bs * 4 etiles(512e) * 32 nsplits), block 256, 2 e per thread.
// ---------------------------------------------------------------------------
__global__ __launch_bounds__(256) void k_proto1(const float* __restrict__ inc,
                                                const float* __restrict__ Kf,
                                                float* __restrict__ part) {
  __shared__ float k_s[64][P_DIM];
  const int tid = threadIdx.x;
  const int b = blockIdx.x >> 7;
  const int et = (blockIdx.x >> 5) & 3;
  const int ns = blockIdx.x & 31;
  const int e0 = et << 9;
  const int nbase = ns << 7;

  float acc0[P_DIM], acc1[P_DIM];
#pragma unroll
  for (int p = 0; p < P_DIM; ++p) { acc0[p] = 0.f; acc1[p] = 0.f; }

  for (int nt = 0; nt < 2; ++nt) {
    int n0 = nbase + nt * 64;
#pragma unroll
    for (int i = 0; i < 8; ++i) {
      int idx = tid + i * 256;
      ((float*)k_s)[idx] = Kf[((size_t)(b * N_DIM + n0)) * P_DIM + idx];
    }
    __syncthreads();
#pragma unroll 8
    for (int nn = 0; nn < 64; ++nn) {
      const float* irow = inc + ((size_t)(b * N_DIM + n0 + nn)) * E_DIM + e0;
      float va = irow[tid];
      float vb = irow[tid + 256];
      const float4* kv4 = (const float4*)k_s[nn];
#pragma unroll
      for (int q = 0; q < 8; ++q) {
        float4 kv = kv4[q];
        acc0[4 * q + 0] = fmaf(va, kv.x, acc0[4 * q + 0]);
        acc0[4 * q + 1] = fmaf(va, kv.y, acc0[4 * q + 1]);
        acc0[4 * q + 2] = fmaf(va, kv.z, acc0[4 * q + 2]);
        acc0[4 * q + 3] = fmaf(va, kv.w, acc0[4 * q + 3]);
        acc1[4 * q + 0] = fmaf(vb, kv.x, acc1[4 * q + 0]);
        acc1[4 * q + 1] = fmaf(vb, kv.y, acc1[4 * q + 1]);
        acc1[4 * q + 2] = fmaf(vb, kv.z, acc1[4 * q + 2]);
        acc1[4 * q + 3] = fmaf(vb, kv.w, acc1[4 * q + 3]);
      }
    }
    __syncthreads();
  }
  float* dst0 = part + (size_t)ns * (BS * E_DIM * P_DIM) +
                ((size_t)(b * E_DIM + e0 + tid)) * P_DIM;
  float* dst1 = dst0 + 256 * P_DIM;
#pragma unroll
  for (int q = 0; q < 8; ++q) {
    ((float4*)dst0)[q] = make_float4(acc0[4 * q + 0], acc0[4 * q + 1],
                                     acc0[4 * q + 2], acc0[4 * q + 3]);
    ((float4*)dst1)[q] = make_float4(acc1[4 * q + 0], acc1[4 * q + 1],
                                     acc1[4 * q + 2], acc1[4 * q + 3]);
  }
}

// ---------------------------------------------------------------------------
// B2: proto1 = sum of 32 partials.  grid 512, block 256
// ---------------------------------------------------------------------------
__global__ __launch_bounds__(256) void k_red32(const float* __restrict__ part,
                                               float* __restrict__ outp) {
  int g = blockIdx.x * 256 + threadIdx.x;
  float v = 0.f;
#pragma unroll
  for (int s = 0; s < NS1; ++s)
    v += part[(size_t)s * (BS * E_DIM * P_DIM) + g];
  outp[g] = v;
}

// ---------------------------------------------------------------------------
// B3: P2part[fs][b][e][p] = sum_{f in 256-chunk} ied[b][e][f]*proto1[b][f][p]
// grid 256 (= bs * 16 etiles(128e) * 8 fsplits), block 256, [2e][8p]/thread.
// ---------------------------------------------------------------------------
__global__ __launch_bounds__(256) void k_proto2(const float* __restrict__ ied,
                                                const float* __restrict__ proto1,
                                                float* __restrict__ part) {
  __shared__ float inv_s[128][33];
  __shared__ float p1_s[32][P_DIM];
  const int tid = threadIdx.x;
  const int b = blockIdx.x >> 7;
  const int et = (blockIdx.x >> 3) & 15;
  const int fs = blockIdx.x & 7;
  const int e0 = et << 7;
  const int fbase = fs << 8;
  const int e_l = tid & 63, pg = tid >> 6;

  float acc0[8], acc1[8];
#pragma unroll
  for (int q = 0; q < 8; ++q) { acc0[q] = 0.f; acc1[q] = 0.f; }

  for (int ft = 0; ft < 8; ++ft) {
    int f0 = fbase + ft * 32;
    __syncthreads();
#pragma unroll
    for (int i = 0; i < 16; ++i) {
      int idx = tid + i * 256;
      int e_r = idx >> 5, f_l = idx & 31;
      inv_s[e_r][f_l] =
          ied[((size_t)(b * E_DIM + e0 + e_r)) * E_DIM + f0 + f_l];
    }
#pragma unroll
    for (int i = 0; i < 4; ++i) {
      int idx = tid + i * 256;
      ((float*)p1_s)[idx] = proto1[((size_t)(b * E_DIM + f0)) * P_DIM + idx];
    }
    __syncthreads();
#pragma unroll
    for (int ff = 0; ff < 32; ++ff) {
      float a0 = inv_s[e_l][ff];
      float a1 = inv_s[e_l + 64][ff];
      const float4* pv4 = (const float4*)&p1_s[ff][pg * 8];
      float4 pv0 = pv4[0], pv1 = pv4[1];
      acc0[0] = fmaf(a0, pv0.x, acc0[0]);
      acc0[1] = fmaf(a0, pv0.y, acc0[1]);
      acc0[2] = fmaf(a0, pv0.z, acc0[2]);
      acc0[3] = fmaf(a0, pv0.w, acc0[3]);
      acc0[4] = fmaf(a0, pv1.x, acc0[4]);
      acc0[5] = fmaf(a0, pv1.y, acc0[5]);
      acc0[6] = fmaf(a0, pv1.z, acc0[6]);
      acc0[7] = fmaf(a0, pv1.w, acc0[7]);
      acc1[0] = fmaf(a1, pv0.x, acc1[0]);
      acc1[1] = fmaf(a1, pv0.y, acc1[1]);
      acc1[2] = fmaf(a1, pv0.z, acc1[2]);
      acc1[3] = fmaf(a1, pv0.w, acc1[3]);
      acc1[4] = fmaf(a1, pv1.x, acc1[4]);
      acc1[5] = fmaf(a1, pv1.y, acc1[5]);
      acc1[6] = fmaf(a1, pv1.z, acc1[6]);
      acc1[7] = fmaf(a1, pv1.w, acc1[7]);
    }
  }
  float* dst0 = part + (size_t)fs * (BS * E_DIM * P_DIM) +
                ((size_t)(b * E_DIM + e0 + e_l)) * P_DIM + pg * 8;
  float* dst1 = dst0 + 64 * P_DIM;
  ((float4*)dst0)[0] = make_float4(acc0[0], acc0[1], acc0[2], acc0[3]);
  ((float4*)dst0)[1] = make_float4(acc0[4], acc0[5], acc0[6], acc0[7]);
  ((float4*)dst1)[0] = make_float4(acc1[0], acc1[1], acc1[2], acc1[3]);
  ((float4*)dst1)[1] = make_float4(acc1[4], acc1[5], acc1[6], acc1[7]);
}

// ---------------------------------------------------------------------------
// B4: proto = sum of 8 partials; proto_sq = rownorm^2.  grid 512, block 256
// ---------------------------------------------------------------------------
__global__ __launch_bounds__(256) void k_red8sq(const float* __restrict__ part,
                                                float* __restrict__ proto,
                                                float* __restrict__ psq) {
  int g = blockIdx.x * 256 + threadIdx.x;
  float v = 0.f;
#pragma unroll
  for (int s = 0; s < FS2; ++s)
    v += part[(size_t)s * (BS * E_DIM * P_DIM) + g];
  proto[g] = v;
  float q = v * v;
#pragma unroll
  for (int m = 1; m <= 16; m <<= 1) q += __shfl_xor(q, m, 64);
  if ((threadIdx.x & 31) == 0) psq[g >> 5] = q;
}

// ---------------------------------------------------------------------------
// C1: per-(edge, 128-n-chunk) max of g = 2*<proto_e,K_n> - Ksq_n
// grid 512, block 256. 64e x 64n tiles, 4x4 microtile, p-major LDS.
// (R3-proven version: 16 acc VGPRs, no spills.)
// ---------------------------------------------------------------------------
__global__ __launch_bounds__(256) void k_gmax(const float* __restrict__ Kf,
                                              const float* __restrict__ Ksq,
                                              const float* __restrict__ proto,
                                              float* __restrict__ chunkg) {
  __shared__ float a_s[P_DIM][64];
  __shared__ float b_s[P_DIM][64];
  __shared__ float q_s[64];
  const int tid = threadIdx.x;
  const int b = blockIdx.x >> 8;
  const int et = (blockIdx.x >> 3) & 31;
  const int ns = blockIdx.x & 7;
  const int e0 = et << 6;
  const int n0b = ns << 9;

  {
    int p = tid >> 6, e = tid & 63;
#pragma unroll
    for (int r = 0; r < 8; ++r)
      a_s[p + r * 4][e] =
          proto[((size_t)(b * E_DIM + e0 + e)) * P_DIM + p + r * 4];
  }
  const int te = tid >> 4, tn = tid & 15;
  float gm[4];
#pragma unroll
  for (int i = 0; i < 4; ++i) gm[i] = -INFINITY;

  for (int t = 0; t < 8; ++t) {
    const int n0 = n0b + t * 64;
    __syncthreads();
    {
      int p = tid >> 6, n = tid & 63;
#pragma unroll
      for (int r = 0; r < 8; ++r)
        b_s[p + r * 4][n] =
            Kf[((size_t)(b * N_DIM + n0 + n)) * P_DIM + p + r * 4];
      if (tid < 64) q_s[tid] = Ksq[b * N_DIM + n0 + tid];
    }
    __syncthreads();

    float acc[4][4];
#pragma unroll
    for (int i = 0; i < 4; ++i)
#pragma unroll
      for (int j = 0; j < 4; ++j) acc[i][j] = 0.f;

#pragma unroll
    for (int p = 0; p < P_DIM; ++p) {
      float4 av = *(const float4*)&a_s[p][te << 2];
      float4 bv = *(const float4*)&b_s[p][tn << 2];
      acc[0][0] = fmaf(av.x, bv.x, acc[0][0]);
      acc[0][1] = fmaf(av.x, bv.y, acc[0][1]);
      acc[0][2] = fmaf(av.x, bv.z, acc[0][2]);
      acc[0][3] = fmaf(av.x, bv.w, acc[0][3]);
      acc[1][0] = fmaf(av.y, bv.x, acc[1][0]);
      acc[1][1] = fmaf(av.y, bv.y, acc[1][1]);
      acc[1][2] = fmaf(av.y, bv.z, acc[1][2]);
      acc[1][3] = fmaf(av.y, bv.w, acc[1][3]);
      acc[2][0] = fmaf(av.z, bv.x, acc[2][0]);
      acc[2][1] = fmaf(av.z, bv.y, acc[2][1]);
      acc[2][2] = fmaf(av.z, bv.z, acc[2][2]);
      acc[2][3] = fmaf(av.z, bv.w, acc[2][3]);
      acc[3][0] = fmaf(av.w, bv.x, acc[3][0]);
      acc[3][1] = fmaf(av.w, bv.y, acc[3][1]);
      acc[3][2] = fmaf(av.w, bv.z, acc[3][2]);
      acc[3][3] = fmaf(av.w, bv.w, acc[3][3]);
    }
#pragma unroll
    for (int i = 0; i < 4; ++i)
#pragma unroll
      for (int j = 0; j < 4; ++j) {
        float g = fmaf(2.0f, acc[i][j], -q_s[(tn << 2) + j]);
        gm[i] = fmaxf(gm[i], g);
      }

    if (t & 1) {
#pragma unroll
      for (int i = 0; i < 4; ++i) {
        float v = gm[i];
        v = fmaxf(v, __shfl_xor(v, 1, 64));
        v = fmaxf(v, __shfl_xor(v, 2, 64));
        v = fmaxf(v, __shfl_xor(v, 4, 64));
        v = fmaxf(v, __shfl_xor(v, 8, 64));
        if (tn == 0)
          chunkg[((size_t)(b * E_DIM + e0 + (te << 2) + i)) * 32 + (ns << 2) +
                 (t >> 1)] = v;
        gm[i] = -INFINITY;
      }
    }
  }
}

// ---------------------------------------------------------------------------
// C2: per-edge sparse softmax-aggregate. One wave per edge.
// grid 1024, block 256 (4 waves).
// ---------------------------------------------------------------------------
__device__ __forceinline__ float edge_logit(const float* __restrict__ Kb,
                                            const float* __restrict__ Qb,
                                            const float* pr, float psqv,
                                            int n) {
  const float4* kp = (const float4*)(Kb + (size_t)n * P_DIM);
  float i0 = 0.f, i1 = 0.f, i2 = 0.f, i3 = 0.f;
#pragma unroll
  for (int q = 0; q < 8; ++q) {
    float4 kv = kp[q];
    i0 = fmaf(pr[4 * q + 0], kv.x, i0);
    i1 = fmaf(pr[4 * q + 1], kv.y, i1);
    i2 = fmaf(pr[4 * q + 2], kv.z, i2);
    i3 = fmaf(pr[4 * q + 3], kv.w, i3);
  }
  float inner = (i0 + i1) + (i2 + i3);
  float cost = fmaf(-2.0f, inner, psqv + Qb[n]);
  const float tau_eps = 0.1f + 1e-8f;
  return (-cost) / tau_eps;
}

__global__ __launch_bounds__(256) void k_sparse(
    const float* __restrict__ Kf, const float* __restrict__ Ksq,
    const float* __restrict__ proto, const float* __restrict__ psq,
    const float* __restrict__ VT, const float* __restrict__ chunkg,
    float* __restrict__ EF0) {
  const int tid = threadIdx.x;
  const int lane = tid & 63;
  const int eg = blockIdx.x * 4 + (tid >> 6);
  const int b = eg >> 11;
  const float* Kb = Kf + (size_t)b * N_DIM * P_DIM;
  const float* Qb = Ksq + (size_t)b * N_DIM;

  float cg = (lane < 32) ? chunkg[(size_t)eg * 32 + lane] : -INFINITY;
  float gmax = cg;
#pragma unroll
  for (int m = 1; m <= 32; m <<= 1) gmax = fmaxf(gmax, __shfl_xor(gmax, m, 64));
  unsigned long long live = __ballot(cg > gmax - 20.0f);

  float pr[P_DIM];
  const float* pe = proto + (size_t)eg * P_DIM;
#pragma unroll
  for (int p = 0; p < P_DIM; ++p) pr[p] = pe[p];
  const float psqv = psq[eg];

  float L = -INFINITY;
  unsigned long long m0 = live;
  while (m0) {
    int c = __ffsll(m0) - 1;
    m0 &= m0 - 1;
    int n = (c << 7) + lane;
    L = fmaxf(L, edge_logit(Kb, Qb, pr, psqv, n));
    L = fmaxf(L, edge_logit(Kb, Qb, pr, psqv, n + 64));
  }
#pragma unroll
  for (int m = 1; m <= 32; m <<= 1) L = fmaxf(L, __shfl_xor(L, m, 64));

  float4 acc = make_float4(0.f, 0.f, 0.f, 0.f);
  float sw = 0.f;
  const float* Vb = VT + (size_t)b * N_DIM * C_DIM;
  m0 = live;
  while (m0) {
    int c = __ffsll(m0) - 1;
    m0 &= m0 - 1;
#pragma unroll
    for (int h = 0; h < 2; ++h) {
      int n = (c << 7) + (h << 6) + lane;
      float l = edge_logit(Kb, Qb, pr, psqv, n);
      float d = l - L;
      float wgt = (d > -25.0f) ? expf(d) : 0.f;
      sw += wgt;
      unsigned long long hits = __ballot(wgt > 0.f);
      while (hits) {
        int src = __ffsll(hits) - 1;
        hits &= hits - 1;
        float wv = __shfl(wgt, src, 64);
        int nv = (c << 7) + (h << 6) + src;
        const float4 vrow =
            *(const float4*)(Vb + (size_t)nv * C_DIM + (lane << 2));
        acc.x = fmaf(wv, vrow.x, acc.x);
        acc.y = fmaf(wv, vrow.y, acc.y);
        acc.z = fmaf(wv, vrow.z, acc.z);
        acc.w = fmaf(wv, vrow.w, acc.w);
      }
    }
  }
#pragma unroll
  for (int m = 1; m <= 32; m <<= 1) sw += __shfl_xor(sw, m, 64);

  float* dst = EF0 + (size_t)eg * C_DIM + (lane << 2);
  *(float4*)dst =
      make_float4(acc.x / sw, acc.y / sw, acc.z / sw, acc.w / sw);
}

// ---------------------------------------------------------------------------
// C3: EF0t[b][c][f] = bf16(EF0[b][f][c]).  grid 256, block 256, 64x64 tiles
// ---------------------------------------------------------------------------
__global__ __launch_bounds__(256) void k_ef0t(const float* __restrict__ EF0,
                                              short* __restrict__ EF0t) {
  __shared__ short sh[64][72];
  const int tid = threadIdx.x;
  const int b = blockIdx.x >> 7;
  const int ft = (blockIdx.x >> 2) & 31;
  const int ct = blockIdx.x & 3;
  const int f0 = ft << 6, c0 = ct << 6;
#pragma unroll
  for (int i = 0; i < 4; ++i) {
    int idx = tid + i * 256;
    int f_l = idx >> 4, cc = idx & 15;
    float4 v =
        *(const float4*)&EF0[((size_t)(b * E_DIM + f0 + f_l)) * C_DIM + c0 +
                             cc * 4];
    sh[cc * 4 + 0][f_l] = (short)f2bf(v.x);
    sh[cc * 4 + 1][f_l] = (short)f2bf(v.y);
    sh[cc * 4 + 2][f_l] = (short)f2bf(v.z);
    sh[cc * 4 + 3][f_l] = (short)f2bf(v.w);
  }
  __syncthreads();
#pragma unroll
  for (int i = 0; i < 2; ++i) {
    int idx = tid + i * 256;
    int c_l = idx >> 3, ch = idx & 7;
    short8 v = *(const short8*)&sh[c_l][ch * 8];
    *(short8*)&EF0t[((size_t)(b * C_DIM + c0 + c_l)) * E_DIM + f0 + ch * 8] = v;
  }
}

// ---------------------------------------------------------------------------
// D: bf16 MFMA GEMM. partOut[ks][b][c][e] = sum_{f in 1024-chunk}
//    ied[b][e][f] * EF0[b][f][c], via D[e][c] = A[e][f]*Bt[c][f] tiles.
// grid 512, block 256 (4 waves). Tile 64e x 64c, BK=64, wave quad 32x32.
// LDS XOR-swizzle (byte ^= (row&7)<<4) -> conflict-free ds_read_b128.
// ---------------------------------------------------------------------------
__device__ __forceinline__ short8 lds_frag(const short* s, int row, int k) {
  int off = (((row << 6) + k) << 1) ^ ((row & 7) << 4);
  return *(const short8*)((const char*)s + off);
}
__device__ __forceinline__ void lds_put(short* s, int row, int k, short8 v) {
  int off = (((row << 6) + k) << 1) ^ ((row & 7) << 4);
  *(short8*)((char*)s + off) = v;
}

__global__ __launch_bounds__(256) void k_final_mfma(
    const short* __restrict__ Ah, const short* __restrict__ Bh,
    float* __restrict__ part) {
  __shared__ short As[64 * 64];
  __shared__ short Bs[64 * 64];
  __shared__ float Cs[64][68];

  const int tid = threadIdx.x;
  const int lane = tid & 63;
  const int w = tid >> 6;
  const int ks = blockIdx.x & 1;
  const int ct = (blockIdx.x >> 1) & 3;
  const int et = (blockIdx.x >> 3) & 31;
  const int b = blockIdx.x >> 8;
  const int e0 = et << 6, c0 = ct << 6;
  const int fbase = ks << 10;

  const int we = (w >> 1) << 5;   // wave e-quadrant offset
  const int wc = (w & 1) << 5;    // wave c-quadrant offset
  const int row = tid >> 2, ch = tid & 3;

  const short* gA = Ah + ((size_t)(b * E_DIM + e0 + row)) * E_DIM + fbase;
  const short* gB = Bh + ((size_t)(b * C_DIM + c0 + row)) * E_DIM + fbase;

  f32x4 z = {0.f, 0.f, 0.f, 0.f};
  f32x4 acc00 = z, acc01 = z, acc10 = z, acc11 = z;

  for (int kt = 0; kt < 16; ++kt) {
    const int f0 = kt << 6;
    const short8* pa = (const short8*)(gA + f0 + ch * 16);
    const short8* pb = (const short8*)(gB + f0 + ch * 16);
    short8 a0 = pa[0], a1 = pa[1];
    short8 b0 = pb[0], b1 = pb[1];
    lds_put(As, row, ch * 16, a0);
    lds_put(As, row, ch * 16 + 8, a1);
    lds_put(Bs, row, ch * 16, b0);
    lds_put(Bs, row, ch * 16 + 8, b1);
    __syncthreads();
#pragma unroll
    for (int s = 0; s < 2; ++s) {
      const int kb = (s << 5) + ((lane >> 4) << 3);
      short8 fa0 = lds_frag(As, we + (lane & 15), kb);
      short8 fa1 = lds_frag(As, we + 16 + (lane & 15), kb);
      short8 fb0 = lds_frag(Bs, wc + (lane & 15), kb);
      short8 fb1 = lds_frag(Bs, wc + 16 + (lane & 15), kb);
      acc00 = __builtin_amdgcn_mfma_f32_16x16x32_bf16(fa0, fb0, acc00, 0, 0, 0);
      acc01 = __builtin_amdgcn_mfma_f32_16x16x32_bf16(fa0, fb1, acc01, 0, 0, 0);
      acc10 = __builtin_amdgcn_mfma_f32_16x16x32_bf16(fa1, fb0, acc10, 0, 0, 0);
      acc11 = __builtin_amdgcn_mfma_f32_16x16x32_bf16(fa1, fb1, acc11, 0, 0, 0);
    }
    __syncthreads();
  }

  // epilogue: stage transposed [c][e] in LDS, then coalesced fp32 writes
  const int fr = lane & 15, fq = lane >> 4;
#pragma unroll
  for (int r = 0; r < 4; ++r) {
    Cs[wc + fr][we + fq * 4 + r] = acc00[r];
    Cs[wc + 16 + fr][we + fq * 4 + r] = acc01[r];
    Cs[wc + fr][we + 16 + fq * 4 + r] = acc10[r];
    Cs[wc + 16 + fr][we + 16 + fq * 4 + r] = acc11[r];
  }
  __syncthreads();
  {
    const int c_l = tid >> 2, cch = tid & 3;
    float* dst = part + (size_t)ks * (BS * C_DIM * E_DIM) +
                 ((size_t)(b * C_DIM + c0 + c_l)) * E_DIM + e0;
#pragma unroll
    for (int r = 0; r < 4; ++r) {
      float4 v = *(const float4*)&Cs[c_l][cch * 16 + r * 4];
      *(float4*)&dst[cch * 16 + r * 4] = v;
    }
  }
}

// ---------------------------------------------------------------------------
// D2: out = sum of KS2 partials (float4).  grid 1024, block 256
// ---------------------------------------------------------------------------
__global__ __launch_bounds__(256) void k_redout(const float* __restrict__ part,
                                                float* __restrict__ out) {
  int g = blockIdx.x * 256 + threadIdx.x;
  const float4* p4 = (const float4*)part;
  float4 v = p4[g];
#pragma unroll
  for (int s = 1; s < KS2; ++s) {
    float4 w = p4[(size_t)s * (BS * C_DIM * E_DIM / 4) + g];
    v.x += w.x; v.y += w.y; v.z += w.z; v.w += w.w;
  }
  ((float4*)out)[g] = v;
}

// ---------------------------------------------------------------------------
extern "C" void kernel_launch(void* const* d_in, const int* in_sizes, int n_in,
                              void* d_out, int out_size, void* d_ws,
                              size_t ws_size, hipStream_t stream) {
  (void)in_sizes; (void)n_in; (void)out_size; (void)ws_size;
  const float* vf  = (const float*)d_in[0];
  const float* inc = (const float*)d_in[1];
  const float* ied = (const float*)d_in[2];
  const float* pw  = (const float*)d_in[5];
  const float* gm  = (const float*)d_in[6];
  const float* bt  = (const float*)d_in[7];
  const float* mn  = (const float*)d_in[8];
  const float* vr  = (const float*)d_in[9];
  float* out = (float*)d_out;

  float* ws = (float*)d_ws;
  float* VT      = ws;                  // 2,097,152 f
  float* Kf      = VT + 2097152;        //   262,144
  float* Ksq     = Kf + 262144;         //     8,192
  float* proto1  = Ksq + 8192;          //   131,072
  float* proto   = proto1 + 131072;     //   131,072
  float* psq     = proto + 131072;      //     4,096
  float* P1p     = psq + 4096;          // 32*131,072 = 4,194,304
  float* partOut = P1p;                 // alias: 2*1,048,576 (disjoint lifetime)
  float* P2p     = P1p + 4194304;       //  8*131,072 = 1,048,576
  float* EF0     = P2p + 1048576;       // 1,048,576
  float* chunkg  = EF0 + 1048576;       //   131,072
  short* ied_h   = (short*)(chunkg + 131072);  // 8,388,608 shorts
  short* EF0t    = (short*)(chunkg + 131072 + 4194304);  // 1,048,576 shorts
  // total ~55.2 MB

  k_proj<<<dim3(128), dim3(256), 0, stream>>>(vf, pw, gm, bt, mn, vr, Kf, Ksq);
  k_transpose<<<dim3(512), dim3(256), 0, stream>>>(vf, VT);
  k_tobf<<<dim3(4096), dim3(256), 0, stream>>>(ied, ied_h);
  k_proto1<<<dim3(256), dim3(256), 0, stream>>>(inc, Kf, P1p);
  k_red32<<<dim3(512), dim3(256), 0, stream>>>(P1p, proto1);
  k_proto2<<<dim3(256), dim3(256), 0, stream>>>(ied, proto1, P2p);
  k_red8sq<<<dim3(512), dim3(256), 0, stream>>>(P2p, proto, psq);
  k_gmax<<<dim3(512), dim3(256), 0, stream>>>(Kf, Ksq, proto, chunkg);
  k_sparse<<<dim3(1024), dim3(256), 0, stream>>>(Kf, Ksq, proto, psq, VT,
                                                 chunkg, EF0);
  k_ef0t<<<dim3(256), dim3(256), 0, stream>>>(EF0, EF0t);
  k_final_mfma<<<dim3(512), dim3(256), 0, stream>>>(ied_h, EF0t, partOut);
  k_redout<<<dim3(1024), dim3(256), 0, stream>>>(partOut, out);
}

// Round 8
// 158.673 us; speedup vs baseline: 3.1459x; 1.0146x over previous
//
#include <hip/hip_runtime.h>
#include <math.h>

#define BS 2
#define C_DIM 256
#define N_DIM 4096
#define E_DIM 2048
#define P_DIM 32
#define NS1 32   // n-splits for proto1
#define FS2 8    // f-splits for proto2

typedef __attribute__((ext_vector_type(8))) short short8;
typedef __attribute__((ext_vector_type(4))) float f32x4;

__device__ __forceinline__ unsigned short f2bf(float f) {
  unsigned u = __float_as_uint(f);
  return (unsigned short)((u + 0x7FFFu + ((u >> 16) & 1u)) >> 16);
}

// ---------------------------------------------------------------------------
// A: K[b][n][p] = BN(proj_w @ vf), Ksq[b][n] = sum_p K^2.  grid 128, block 256
// ---------------------------------------------------------------------------
__global__ __launch_bounds__(256) void k_proj(
    const float* __restrict__ vf, const float* __restrict__ pw,
    const float* __restrict__ gamma, const float* __restrict__ beta,
    const float* __restrict__ mean, const float* __restrict__ var,
    float* __restrict__ Kf, float* __restrict__ Ksq) {
  __shared__ float w_s[P_DIM * C_DIM];
  __shared__ float part_s[4][64][P_DIM + 1];
  __shared__ float kt_s[64][P_DIM + 1];
  __shared__ float sc_s[P_DIM], sb_s[P_DIM], sm_s[P_DIM];

  const int tid = threadIdx.x;
  const int b = blockIdx.x >> 6;
  const int n0 = (blockIdx.x & 63) << 6;

  for (int i = tid; i < P_DIM * C_DIM; i += 256) w_s[i] = pw[i];
  if (tid < P_DIM) {
    sc_s[tid] = gamma[tid] / sqrtf(var[tid] + 1e-5f);
    sb_s[tid] = beta[tid];
    sm_s[tid] = mean[tid];
  }
  __syncthreads();

  const int nl = tid & 63, cs = tid >> 6;
  const float* vbase = vf + (size_t)b * C_DIM * N_DIM + n0 + nl;
  float acc[P_DIM];
#pragma unroll
  for (int p = 0; p < P_DIM; ++p) acc[p] = 0.f;
#pragma unroll 4
  for (int cc = 0; cc < 64; ++cc) {
    int c = cs * 64 + cc;
    float v = vbase[(size_t)c * N_DIM];
    const float* wc = &w_s[c];
#pragma unroll
    for (int p = 0; p < P_DIM; ++p) acc[p] = fmaf(wc[p * C_DIM], v, acc[p]);
  }
#pragma unroll
  for (int p = 0; p < P_DIM; ++p) part_s[cs][nl][p] = acc[p];
  __syncthreads();

  for (int i = tid; i < 64 * P_DIM; i += 256) {
    int n_l = i >> 5, p = i & 31;
    float s = ((part_s[0][n_l][p] + part_s[1][n_l][p]) + part_s[2][n_l][p]) +
              part_s[3][n_l][p];
    float k = (s - sm_s[p]) * sc_s[p] + sb_s[p];
    Kf[((size_t)(b * N_DIM + n0 + n_l)) * P_DIM + p] = k;
    kt_s[n_l][p] = k;
  }
  __syncthreads();
  if (tid < 64) {
    float q = 0.f;
#pragma unroll
    for (int p = 0; p < P_DIM; ++p) q = fmaf(kt_s[tid][p], kt_s[tid][p], q);
    Ksq[b * N_DIM + n0 + tid] = q;
  }
}

// ---------------------------------------------------------------------------
// A2: VT[b][n][c] = vf[b][c][n].  grid 512, block 256
// ---------------------------------------------------------------------------
__global__ __launch_bounds__(256) void k_transpose(const float* __restrict__ vf,
                                                   float* __restrict__ VT) {
  __shared__ float t_s[64][65];
  const int tid = threadIdx.x;
  const int b = blockIdx.x >> 8;
  const int n0 = ((blockIdx.x >> 2) & 63) << 6;
  const int c0 = (blockIdx.x & 3) << 6;
  const float* src = vf + (size_t)b * C_DIM * N_DIM;
#pragma unroll
  for (int i = 0; i < 16; ++i) {
    int idx = tid + i * 256;
    int n_l = idx & 63, c_l = idx >> 6;
    t_s[c_l][n_l] = src[(size_t)(c0 + c_l) * N_DIM + n0 + n_l];
  }
  __syncthreads();
  float* dst = VT + (size_t)b * N_DIM * C_DIM;
#pragma unroll
  for (int i = 0; i < 16; ++i) {
    int idx = tid + i * 256;
    int c_l = idx & 63, n_l = idx >> 6;
    dst[(size_t)(n0 + n_l) * C_DIM + c0 + c_l] = t_s[c_l][n_l];
  }
}

// ---------------------------------------------------------------------------
// B1: P1part[ns][b][e][p] = sum_{n in 128-chunk} inc[b][n][e]*K[b][n][p]
// grid 256 (= bs * 4 etiles(512e) * 32 nsplits), block 256, 2 e per thread.
// ---------------------------------------------------------------------------
__global__ __launch_bounds__(256) void k_proto1(const float* __restrict__ inc,
                                                const float* __restrict__ Kf,
                                                float* __restrict__ part) {
  __shared__ float k_s[64][P_DIM];
  const int tid = threadIdx.x;
  const int b = blockIdx.x >> 7;
  const int et = (blockIdx.x >> 5) & 3;
  const int ns = blockIdx.x & 31;
  const int e0 = et << 9;
  const int nbase = ns << 7;

  float acc0[P_DIM], acc1[P_DIM];
#pragma unroll
  for (int p = 0; p < P_DIM; ++p) { acc0[p] = 0.f; acc1[p] = 0.f; }

  for (int nt = 0; nt < 2; ++nt) {
    int n0 = nbase + nt * 64;
#pragma unroll
    for (int i = 0; i < 8; ++i) {
      int idx = tid + i * 256;
      ((float*)k_s)[idx] = Kf[((size_t)(b * N_DIM + n0)) * P_DIM + idx];
    }
    __syncthreads();
#pragma unroll 8
    for (int nn = 0; nn < 64; ++nn) {
      const float* irow = inc + ((size_t)(b * N_DIM + n0 + nn)) * E_DIM + e0;
      float va = irow[tid];
      float vb = irow[tid + 256];
      const float4* kv4 = (const float4*)k_s[nn];
#pragma unroll
      for (int q = 0; q < 8; ++q) {
        float4 kv = kv4[q];
        acc0[4 * q + 0] = fmaf(va, kv.x, acc0[4 * q + 0]);
        acc0[4 * q + 1] = fmaf(va, kv.y, acc0[4 * q + 1]);
        acc0[4 * q + 2] = fmaf(va, kv.z, acc0[4 * q + 2]);
        acc0[4 * q + 3] = fmaf(va, kv.w, acc0[4 * q + 3]);
        acc1[4 * q + 0] = fmaf(vb, kv.x, acc1[4 * q + 0]);
        acc1[4 * q + 1] = fmaf(vb, kv.y, acc1[4 * q + 1]);
        acc1[4 * q + 2] = fmaf(vb, kv.z, acc1[4 * q + 2]);
        acc1[4 * q + 3] = fmaf(vb, kv.w, acc1[4 * q + 3]);
      }
    }
    __syncthreads();
  }
  float* dst0 = part + (size_t)ns * (BS * E_DIM * P_DIM) +
                ((size_t)(b * E_DIM + e0 + tid)) * P_DIM;
  float* dst1 = dst0 + 256 * P_DIM;
#pragma unroll
  for (int q = 0; q < 8; ++q) {
    ((float4*)dst0)[q] = make_float4(acc0[4 * q + 0], acc0[4 * q + 1],
                                     acc0[4 * q + 2], acc0[4 * q + 3]);
    ((float4*)dst1)[q] = make_float4(acc1[4 * q + 0], acc1[4 * q + 1],
                                     acc1[4 * q + 2], acc1[4 * q + 3]);
  }
}

// ---------------------------------------------------------------------------
// B2: proto1 = sum of 32 partials.  grid 512, block 256
// ---------------------------------------------------------------------------
__global__ __launch_bounds__(256) void k_red32(const float* __restrict__ part,
                                               float* __restrict__ outp) {
  int g = blockIdx.x * 256 + threadIdx.x;
  float v = 0.f;
#pragma unroll
  for (int s = 0; s < NS1; ++s)
    v += part[(size_t)s * (BS * E_DIM * P_DIM) + g];
  outp[g] = v;
}

// ---------------------------------------------------------------------------
// B3: P2part[fs][b][e][p] = sum_{f in 256-chunk} ied[b][e][f]*proto1[b][f][p]
// grid 256, block 256, [2e][8p]/thread. ALSO emits ied_h = bf16(ied) —
// each ied element is loaded exactly once across this grid.
// ---------------------------------------------------------------------------
__global__ __launch_bounds__(256) void k_proto2(const float* __restrict__ ied,
                                                const float* __restrict__ proto1,
                                                float* __restrict__ part,
                                                short* __restrict__ ied_h) {
  __shared__ float inv_s[128][33];
  __shared__ float p1_s[32][P_DIM];
  const int tid = threadIdx.x;
  const int b = blockIdx.x >> 7;
  const int et = (blockIdx.x >> 3) & 15;
  const int fs = blockIdx.x & 7;
  const int e0 = et << 7;
  const int fbase = fs << 8;
  const int e_l = tid & 63, pg = tid >> 6;

  float acc0[8], acc1[8];
#pragma unroll
  for (int q = 0; q < 8; ++q) { acc0[q] = 0.f; acc1[q] = 0.f; }

  for (int ft = 0; ft < 8; ++ft) {
    int f0 = fbase + ft * 32;
    __syncthreads();
#pragma unroll
    for (int i = 0; i < 16; ++i) {
      int idx = tid + i * 256;
      int e_r = idx >> 5, f_l = idx & 31;
      size_t gidx = ((size_t)(b * E_DIM + e0 + e_r)) * E_DIM + f0 + f_l;
      float v = ied[gidx];
      inv_s[e_r][f_l] = v;
      ied_h[gidx] = (short)f2bf(v);
    }
#pragma unroll
    for (int i = 0; i < 4; ++i) {
      int idx = tid + i * 256;
      ((float*)p1_s)[idx] = proto1[((size_t)(b * E_DIM + f0)) * P_DIM + idx];
    }
    __syncthreads();
#pragma unroll
    for (int ff = 0; ff < 32; ++ff) {
      float a0 = inv_s[e_l][ff];
      float a1 = inv_s[e_l + 64][ff];
      const float4* pv4 = (const float4*)&p1_s[ff][pg * 8];
      float4 pv0 = pv4[0], pv1 = pv4[1];
      acc0[0] = fmaf(a0, pv0.x, acc0[0]);
      acc0[1] = fmaf(a0, pv0.y, acc0[1]);
      acc0[2] = fmaf(a0, pv0.z, acc0[2]);
      acc0[3] = fmaf(a0, pv0.w, acc0[3]);
      acc0[4] = fmaf(a0, pv1.x, acc0[4]);
      acc0[5] = fmaf(a0, pv1.y, acc0[5]);
      acc0[6] = fmaf(a0, pv1.z, acc0[6]);
      acc0[7] = fmaf(a0, pv1.w, acc0[7]);
      acc1[0] = fmaf(a1, pv0.x, acc1[0]);
      acc1[1] = fmaf(a1, pv0.y, acc1[1]);
      acc1[2] = fmaf(a1, pv0.z, acc1[2]);
      acc1[3] = fmaf(a1, pv0.w, acc1[3]);
      acc1[4] = fmaf(a1, pv1.x, acc1[4]);
      acc1[5] = fmaf(a1, pv1.y, acc1[5]);
      acc1[6] = fmaf(a1, pv1.z, acc1[6]);
      acc1[7] = fmaf(a1, pv1.w, acc1[7]);
    }
  }
  float* dst0 = part + (size_t)fs * (BS * E_DIM * P_DIM) +
                ((size_t)(b * E_DIM + e0 + e_l)) * P_DIM + pg * 8;
  float* dst1 = dst0 + 64 * P_DIM;
  ((float4*)dst0)[0] = make_float4(acc0[0], acc0[1], acc0[2], acc0[3]);
  ((float4*)dst0)[1] = make_float4(acc0[4], acc0[5], acc0[6], acc0[7]);
  ((float4*)dst1)[0] = make_float4(acc1[0], acc1[1], acc1[2], acc1[3]);
  ((float4*)dst1)[1] = make_float4(acc1[4], acc1[5], acc1[6], acc1[7]);
}

// ---------------------------------------------------------------------------
// B4: proto = sum of 8 partials; proto_sq = rownorm^2.  grid 512, block 256
// ---------------------------------------------------------------------------
__global__ __launch_bounds__(256) void k_red8sq(const float* __restrict__ part,
                                                float* __restrict__ proto,
                                                float* __restrict__ psq) {
  int g = blockIdx.x * 256 + threadIdx.x;
  float v = 0.f;
#pragma unroll
  for (int s = 0; s < FS2; ++s)
    v += part[(size_t)s * (BS * E_DIM * P_DIM) + g];
  proto[g] = v;
  float q = v * v;
#pragma unroll
  for (int m = 1; m <= 16; m <<= 1) q += __shfl_xor(q, m, 64);
  if ((threadIdx.x & 31) == 0) psq[g >> 5] = q;
}

// ---------------------------------------------------------------------------
// C1: per-(edge, 128-n-chunk) max of g = 2*<proto_e,K_n> - Ksq_n
// grid 512, block 256. 64e x 64n tiles, 4x4 microtile, p-major LDS.
// (R3-proven version: 16 acc VGPRs, no spills.)
// ---------------------------------------------------------------------------
__global__ __launch_bounds__(256) void k_gmax(const float* __restrict__ Kf,
                                              const float* __restrict__ Ksq,
                                              const float* __restrict__ proto,
                                              float* __restrict__ chunkg) {
  __shared__ float a_s[P_DIM][64];
  __shared__ float b_s[P_DIM][64];
  __shared__ float q_s[64];
  const int tid = threadIdx.x;
  const int b = blockIdx.x >> 8;
  const int et = (blockIdx.x >> 3) & 31;
  const int ns = blockIdx.x & 7;
  const int e0 = et << 6;
  const int n0b = ns << 9;

  {
    int p = tid >> 6, e = tid & 63;
#pragma unroll
    for (int r = 0; r < 8; ++r)
      a_s[p + r * 4][e] =
          proto[((size_t)(b * E_DIM + e0 + e)) * P_DIM + p + r * 4];
  }
  const int te = tid >> 4, tn = tid & 15;
  float gm[4];
#pragma unroll
  for (int i = 0; i < 4; ++i) gm[i] = -INFINITY;

  for (int t = 0; t < 8; ++t) {
    const int n0 = n0b + t * 64;
    __syncthreads();
    {
      int p = tid >> 6, n = tid & 63;
#pragma unroll
      for (int r = 0; r < 8; ++r)
        b_s[p + r * 4][n] =
            Kf[((size_t)(b * N_DIM + n0 + n)) * P_DIM + p + r * 4];
      if (tid < 64) q_s[tid] = Ksq[b * N_DIM + n0 + tid];
    }
    __syncthreads();

    float acc[4][4];
#pragma unroll
    for (int i = 0; i < 4; ++i)
#pragma unroll
      for (int j = 0; j < 4; ++j) acc[i][j] = 0.f;

#pragma unroll
    for (int p = 0; p < P_DIM; ++p) {
      float4 av = *(const float4*)&a_s[p][te << 2];
      float4 bv = *(const float4*)&b_s[p][tn << 2];
      acc[0][0] = fmaf(av.x, bv.x, acc[0][0]);
      acc[0][1] = fmaf(av.x, bv.y, acc[0][1]);
      acc[0][2] = fmaf(av.x, bv.z, acc[0][2]);
      acc[0][3] = fmaf(av.x, bv.w, acc[0][3]);
      acc[1][0] = fmaf(av.y, bv.x, acc[1][0]);
      acc[1][1] = fmaf(av.y, bv.y, acc[1][1]);
      acc[1][2] = fmaf(av.y, bv.z, acc[1][2]);
      acc[1][3] = fmaf(av.y, bv.w, acc[1][3]);
      acc[2][0] = fmaf(av.z, bv.x, acc[2][0]);
      acc[2][1] = fmaf(av.z, bv.y, acc[2][1]);
      acc[2][2] = fmaf(av.z, bv.z, acc[2][2]);
      acc[2][3] = fmaf(av.z, bv.w, acc[2][3]);
      acc[3][0] = fmaf(av.w, bv.x, acc[3][0]);
      acc[3][1] = fmaf(av.w, bv.y, acc[3][1]);
      acc[3][2] = fmaf(av.w, bv.z, acc[3][2]);
      acc[3][3] = fmaf(av.w, bv.w, acc[3][3]);
    }
#pragma unroll
    for (int i = 0; i < 4; ++i)
#pragma unroll
      for (int j = 0; j < 4; ++j) {
        float g = fmaf(2.0f, acc[i][j], -q_s[(tn << 2) + j]);
        gm[i] = fmaxf(gm[i], g);
      }

    if (t & 1) {
#pragma unroll
      for (int i = 0; i < 4; ++i) {
        float v = gm[i];
        v = fmaxf(v, __shfl_xor(v, 1, 64));
        v = fmaxf(v, __shfl_xor(v, 2, 64));
        v = fmaxf(v, __shfl_xor(v, 4, 64));
        v = fmaxf(v, __shfl_xor(v, 8, 64));
        if (tn == 0)
          chunkg[((size_t)(b * E_DIM + e0 + (te << 2) + i)) * 32 + (ns << 2) +
                 (t >> 1)] = v;
        gm[i] = -INFINITY;
      }
    }
  }
}

// ---------------------------------------------------------------------------
// C2: per-edge sparse softmax-aggregate. One wave per edge.
// grid 1024, block 256 (4 waves).
// ---------------------------------------------------------------------------
__device__ __forceinline__ float edge_logit(const float* __restrict__ Kb,
                                            const float* __restrict__ Qb,
                                            const float* pr, float psqv,
                                            int n) {
  const float4* kp = (const float4*)(Kb + (size_t)n * P_DIM);
  float i0 = 0.f, i1 = 0.f, i2 = 0.f, i3 = 0.f;
#pragma unroll
  for (int q = 0; q < 8; ++q) {
    float4 kv = kp[q];
    i0 = fmaf(pr[4 * q + 0], kv.x, i0);
    i1 = fmaf(pr[4 * q + 1], kv.y, i1);
    i2 = fmaf(pr[4 * q + 2], kv.z, i2);
    i3 = fmaf(pr[4 * q + 3], kv.w, i3);
  }
  float inner = (i0 + i1) + (i2 + i3);
  float cost = fmaf(-2.0f, inner, psqv + Qb[n]);
  const float tau_eps = 0.1f + 1e-8f;
  return (-cost) / tau_eps;
}

__global__ __launch_bounds__(256) void k_sparse(
    const float* __restrict__ Kf, const float* __restrict__ Ksq,
    const float* __restrict__ proto, const float* __restrict__ psq,
    const float* __restrict__ VT, const float* __restrict__ chunkg,
    float* __restrict__ EF0) {
  const int tid = threadIdx.x;
  const int lane = tid & 63;
  const int eg = blockIdx.x * 4 + (tid >> 6);
  const int b = eg >> 11;
  const float* Kb = Kf + (size_t)b * N_DIM * P_DIM;
  const float* Qb = Ksq + (size_t)b * N_DIM;

  float cg = (lane < 32) ? chunkg[(size_t)eg * 32 + lane] : -INFINITY;
  float gmax = cg;
#pragma unroll
  for (int m = 1; m <= 32; m <<= 1) gmax = fmaxf(gmax, __shfl_xor(gmax, m, 64));
  unsigned long long live = __ballot(cg > gmax - 20.0f);

  float pr[P_DIM];
  const float* pe = proto + (size_t)eg * P_DIM;
#pragma unroll
  for (int p = 0; p < P_DIM; ++p) pr[p] = pe[p];
  const float psqv = psq[eg];

  float L = -INFINITY;
  unsigned long long m0 = live;
  while (m0) {
    int c = __ffsll(m0) - 1;
    m0 &= m0 - 1;
    int n = (c << 7) + lane;
    L = fmaxf(L, edge_logit(Kb, Qb, pr, psqv, n));
    L = fmaxf(L, edge_logit(Kb, Qb, pr, psqv, n + 64));
  }
#pragma unroll
  for (int m = 1; m <= 32; m <<= 1) L = fmaxf(L, __shfl_xor(L, m, 64));

  float4 acc = make_float4(0.f, 0.f, 0.f, 0.f);
  float sw = 0.f;
  const float* Vb = VT + (size_t)b * N_DIM * C_DIM;
  m0 = live;
  while (m0) {
    int c = __ffsll(m0) - 1;
    m0 &= m0 - 1;
#pragma unroll
    for (int h = 0; h < 2; ++h) {
      int n = (c << 7) + (h << 6) + lane;
      float l = edge_logit(Kb, Qb, pr, psqv, n);
      float d = l - L;
      float wgt = (d > -25.0f) ? expf(d) : 0.f;
      sw += wgt;
      unsigned long long hits = __ballot(wgt > 0.f);
      while (hits) {
        int src = __ffsll(hits) - 1;
        hits &= hits - 1;
        float wv = __shfl(wgt, src, 64);
        int nv = (c << 7) + (h << 6) + src;
        const float4 vrow =
            *(const float4*)(Vb + (size_t)nv * C_DIM + (lane << 2));
        acc.x = fmaf(wv, vrow.x, acc.x);
        acc.y = fmaf(wv, vrow.y, acc.y);
        acc.z = fmaf(wv, vrow.z, acc.z);
        acc.w = fmaf(wv, vrow.w, acc.w);
      }
    }
  }
#pragma unroll
  for (int m = 1; m <= 32; m <<= 1) sw += __shfl_xor(sw, m, 64);

  float* dst = EF0 + (size_t)eg * C_DIM + (lane << 2);
  *(float4*)dst =
      make_float4(acc.x / sw, acc.y / sw, acc.z / sw, acc.w / sw);
}

// ---------------------------------------------------------------------------
// C3: EF0t[b][c][f] = bf16(EF0[b][f][c]).  grid 256, block 256, 64x64 tiles
// ---------------------------------------------------------------------------
__global__ __launch_bounds__(256) void k_ef0t(const float* __restrict__ EF0,
                                              short* __restrict__ EF0t) {
  __shared__ short sh[64][72];
  const int tid = threadIdx.x;
  const int b = blockIdx.x >> 7;
  const int ft = (blockIdx.x >> 2) & 31;
  const int ct = blockIdx.x & 3;
  const int f0 = ft << 6, c0 = ct << 6;
#pragma unroll
  for (int i = 0; i < 4; ++i) {
    int idx = tid + i * 256;
    int f_l = idx >> 4, cc = idx & 15;
    float4 v =
        *(const float4*)&EF0[((size_t)(b * E_DIM + f0 + f_l)) * C_DIM + c0 +
                             cc * 4];
    sh[cc * 4 + 0][f_l] = (short)f2bf(v.x);
    sh[cc * 4 + 1][f_l] = (short)f2bf(v.y);
    sh[cc * 4 + 2][f_l] = (short)f2bf(v.z);
    sh[cc * 4 + 3][f_l] = (short)f2bf(v.w);
  }
  __syncthreads();
#pragma unroll
  for (int i = 0; i < 2; ++i) {
    int idx = tid + i * 256;
    int c_l = idx >> 3, ch = idx & 7;
    short8 v = *(const short8*)&sh[c_l][ch * 8];
    *(short8*)&EF0t[((size_t)(b * C_DIM + c0 + c_l)) * E_DIM + f0 + ch * 8] = v;
  }
}

// ---------------------------------------------------------------------------
// D: bf16 MFMA GEMM, full K (no split), double-buffered LDS + reg prefetch.
// out[b][c][e] = sum_f ied[b][e][f] * EF0[b][f][c].
// grid 256 (= 2b * 32et * 4ct), block 256 (4 waves). Tile 64e x 64c, BK=64,
// wave quad 32x32. LDS XOR-swizzle (byte ^= (row&7)<<4), 1 barrier/K-step.
// ---------------------------------------------------------------------------
__device__ __forceinline__ short8 lds_frag(const short* s, int row, int k) {
  int off = (((row << 6) + k) << 1) ^ ((row & 7) << 4);
  return *(const short8*)((const char*)s + off);
}
__device__ __forceinline__ void lds_put(short* s, int row, int k, short8 v) {
  int off = (((row << 6) + k) << 1) ^ ((row & 7) << 4);
  *(short8*)((char*)s + off) = v;
}

__global__ __launch_bounds__(256) void k_final_mfma(
    const short* __restrict__ Ah, const short* __restrict__ Bh,
    float* __restrict__ out) {
  __shared__ short As[2][64 * 64];
  __shared__ short Bs[2][64 * 64];
  __shared__ float Cs[64][68];

  const int tid = threadIdx.x;
  const int lane = tid & 63;
  const int w = tid >> 6;
  const int ct = blockIdx.x & 3;
  const int et = (blockIdx.x >> 2) & 31;
  const int b = blockIdx.x >> 7;
  const int e0 = et << 6, c0 = ct << 6;

  const int we = (w >> 1) << 5;   // wave e-quadrant offset
  const int wc = (w & 1) << 5;    // wave c-quadrant offset
  const int row = tid >> 2, ch = tid & 3;

  const short* gA = Ah + ((size_t)(b * E_DIM + e0 + row)) * E_DIM;
  const short* gB = Bh + ((size_t)(b * C_DIM + c0 + row)) * E_DIM;

  f32x4 z = {0.f, 0.f, 0.f, 0.f};
  f32x4 acc00 = z, acc01 = z, acc10 = z, acc11 = z;

  // prologue: tile 0 -> LDS[0]
  {
    const short8* pa = (const short8*)(gA + ch * 16);
    const short8* pb = (const short8*)(gB + ch * 16);
    short8 a0 = pa[0], a1 = pa[1];
    short8 b0 = pb[0], b1 = pb[1];
    lds_put(As[0], row, ch * 16, a0);
    lds_put(As[0], row, ch * 16 + 8, a1);
    lds_put(Bs[0], row, ch * 16, b0);
    lds_put(Bs[0], row, ch * 16 + 8, b1);
  }
  __syncthreads();

  for (int kt = 0; kt < 32; ++kt) {
    const int cur = kt & 1;
    short8 na0, na1, nb0, nb1;
    if (kt < 31) {  // issue next-tile loads early (hide HBM under MFMA)
      const int f1 = (kt + 1) << 6;
      const short8* pa = (const short8*)(gA + f1 + ch * 16);
      const short8* pb = (const short8*)(gB + f1 + ch * 16);
      na0 = pa[0]; na1 = pa[1]; nb0 = pb[0]; nb1 = pb[1];
    }
#pragma unroll
    for (int s = 0; s < 2; ++s) {
      const int kb = (s << 5) + ((lane >> 4) << 3);
      short8 fa0 = lds_frag(As[cur], we + (lane & 15), kb);
      short8 fa1 = lds_frag(As[cur], we + 16 + (lane & 15), kb);
      short8 fb0 = lds_frag(Bs[cur], wc + (lane & 15), kb);
      short8 fb1 = lds_frag(Bs[cur], wc + 16 + (lane & 15), kb);
      acc00 = __builtin_amdgcn_mfma_f32_16x16x32_bf16(fa0, fb0, acc00, 0, 0, 0);
      acc01 = __builtin_amdgcn_mfma_f32_16x16x32_bf16(fa0, fb1, acc01, 0, 0, 0);
      acc10 = __builtin_amdgcn_mfma_f32_16x16x32_bf16(fa1, fb0, acc10, 0, 0, 0);
      acc11 = __builtin_amdgcn_mfma_f32_16x16x32_bf16(fa1, fb1, acc11, 0, 0, 0);
    }
    if (kt < 31) {  // write into the buffer last read at kt-1 (barrier-safe)
      lds_put(As[cur ^ 1], row, ch * 16, na0);
      lds_put(As[cur ^ 1], row, ch * 16 + 8, na1);
      lds_put(Bs[cur ^ 1], row, ch * 16, nb0);
      lds_put(Bs[cur ^ 1], row, ch * 16 + 8, nb1);
    }
    __syncthreads();
  }

  // epilogue: stage transposed [c][e] in LDS, then coalesced fp32 writes
  const int fr = lane & 15, fq = lane >> 4;
#pragma unroll
  for (int r = 0; r < 4; ++r) {
    Cs[wc + fr][we + fq * 4 + r] = acc00[r];
    Cs[wc + 16 + fr][we + fq * 4 + r] = acc01[r];
    Cs[wc + fr][we + 16 + fq * 4 + r] = acc10[r];
    Cs[wc + 16 + fr][we + 16 + fq * 4 + r] = acc11[r];
  }
  __syncthreads();
  {
    const int c_l = tid >> 2, cch = tid & 3;
    float* dst = out + ((size_t)(b * C_DIM + c0 + c_l)) * E_DIM + e0;
#pragma unroll
    for (int r = 0; r < 4; ++r) {
      float4 v = *(const float4*)&Cs[c_l][cch * 16 + r * 4];
      *(float4*)&dst[cch * 16 + r * 4] = v;
    }
  }
}

// ---------------------------------------------------------------------------
extern "C" void kernel_launch(void* const* d_in, const int* in_sizes, int n_in,
                              void* d_out, int out_size, void* d_ws,
                              size_t ws_size, hipStream_t stream) {
  (void)in_sizes; (void)n_in; (void)out_size; (void)ws_size;
  const float* vf  = (const float*)d_in[0];
  const float* inc = (const float*)d_in[1];
  const float* ied = (const float*)d_in[2];
  const float* pw  = (const float*)d_in[5];
  const float* gm  = (const float*)d_in[6];
  const float* bt  = (const float*)d_in[7];
  const float* mn  = (const float*)d_in[8];
  const float* vr  = (const float*)d_in[9];
  float* out = (float*)d_out;

  float* ws = (float*)d_ws;
  float* VT      = ws;                  // 2,097,152 f
  float* Kf      = VT + 2097152;        //   262,144
  float* Ksq     = Kf + 262144;         //     8,192
  float* proto1  = Ksq + 8192;          //   131,072
  float* proto   = proto1 + 131072;     //   131,072
  float* psq     = proto + 131072;      //     4,096
  float* P1p     = psq + 4096;          // 32*131,072 = 4,194,304
  float* P2p     = P1p + 4194304;       //  8*131,072 = 1,048,576
  float* EF0     = P2p + 1048576;       // 1,048,576
  float* chunkg  = EF0 + 1048576;       //   131,072
  short* ied_h   = (short*)(chunkg + 131072);            // 8,388,608 shorts
  short* EF0t    = (short*)(chunkg + 131072 + 4194304);  // 1,048,576 shorts
  // total ~47 MB

  k_proj<<<dim3(128), dim3(256), 0, stream>>>(vf, pw, gm, bt, mn, vr, Kf, Ksq);
  k_transpose<<<dim3(512), dim3(256), 0, stream>>>(vf, VT);
  k_proto1<<<dim3(256), dim3(256), 0, stream>>>(inc, Kf, P1p);
  k_red32<<<dim3(512), dim3(256), 0, stream>>>(P1p, proto1);
  k_proto2<<<dim3(256), dim3(256), 0, stream>>>(ied, proto1, P2p, ied_h);
  k_red8sq<<<dim3(512), dim3(256), 0, stream>>>(P2p, proto, psq);
  k_gmax<<<dim3(512), dim3(256), 0, stream>>>(Kf, Ksq, proto, chunkg);
  k_sparse<<<dim3(1024), dim3(256), 0, stream>>>(Kf, Ksq, proto, psq, VT,
                                                 chunkg, EF0);
  k_ef0t<<<dim3(256), dim3(256), 0, stream>>>(EF0, EF0t);
  k_final_mfma<<<dim3(256), dim3(256), 0, stream>>>(ied_h, EF0t, out);
}